// Round 1
// baseline (959.423 us; speedup 1.0000x reference)
//
#include <hip/hip_runtime.h>
#include <hip/hip_bf16.h>

#define TOTAL_N   131072
#define NEDGE     4194304
#define NPG       2048
#define IN_DIM_K  128
#define HID_K     256
#define EMB_K     64
#define NAGENT    64

#define E0CAP     4096
#define F1CAP     4096
#define E1CAP     131072

// ---------------- workspace layout (bytes) ----------------
// zeroed every launch:
//   0        : out_deg   int[TOTAL_N]          512K
//   524288   : in_deg    int[TOTAL_N]          512K
//   1048576  : flag      int[TOTAL_N]          512K
//   1572864  : counters  int[256]              1K   ([0]=nE0 [1]=nF1 [2]=nE1)
//   1573888  : agg1      float[F1CAP*HID]      4M
//   5768192  : agg2      float[NAGENT*HID]     64K
//   zero span = [0, 5833728)
// not zeroed (fully written before read):
//   5833728  : loc       int[TOTAL_N]          512K
//   6358016  : nodeOfLoc int[F1CAP]            16K
//   6374400  : e0src     int[E0CAP]            16K
//   6390784  : e0agent   int[E0CAP]            16K
//   6407168  : e1src     int[E1CAP]            512K
//   6931456  : e1loc     int[E1CAP]            512K
//   7455744  : h1        float[F1CAP*HID]      4M
// total = 11650048 bytes (~11.6 MB)

#define WS_ZERO_BYTES 5833728

// K1: full-degree count + select edges into agent nodes, mark their srcs
__global__ __launch_bounds__(256) void k_deg_select(
    const int* __restrict__ src, const int* __restrict__ dst,
    int* __restrict__ out_deg, int* __restrict__ in_deg,
    int* __restrict__ flag, int* __restrict__ counters,
    int* __restrict__ e0src, int* __restrict__ e0agent)
{
    int e = blockIdx.x * 256 + threadIdx.x;
    if (e >= NEDGE) return;
    int s = src[e], d = dst[e];
    atomicAdd(&out_deg[s], 1);
    atomicAdd(&in_deg[d], 1);
    if ((d & (NPG - 1)) == 0) {
        int i = atomicAdd(&counters[0], 1);
        if (i < E0CAP) { e0src[i] = s; e0agent[i] = d >> 11; }
        flag[s] = 1;   // benign race, idempotent
    }
}

// K2: compact frontier F1: assign local ids
__global__ __launch_bounds__(256) void k_compact(
    const int* __restrict__ flag, int* __restrict__ loc,
    int* __restrict__ nodeOfLoc, int* __restrict__ counters)
{
    int v = blockIdx.x * 256 + threadIdx.x;
    if (v >= TOTAL_N) return;
    int l = -1;
    if (flag[v]) {
        int id = atomicAdd(&counters[1], 1);
        if (id < F1CAP) { l = id; nodeOfLoc[id] = v; }
    }
    loc[v] = l;
}

// K3: select edges whose dst is in F1
__global__ __launch_bounds__(256) void k_e1_select(
    const int* __restrict__ src, const int* __restrict__ dst,
    const int* __restrict__ loc, int* __restrict__ counters,
    int* __restrict__ e1src, int* __restrict__ e1loc)
{
    int e = blockIdx.x * 256 + threadIdx.x;
    if (e >= NEDGE) return;
    int l = loc[dst[e]];
    if (l >= 0) {
        int i = atomicAdd(&counters[2], 1);
        if (i < E1CAP) { e1src[i] = src[e]; e1loc[i] = l; }
    }
}

// K4: per selected edge: h0 = relu(x[src]@w_lin + b_lin); agg1[loc[dst]] += out_norm[src]*h0
// 16 edges per 256-thread block; thread j owns output column j.
__global__ __launch_bounds__(256) void k_edge_gemm(
    const float* __restrict__ x, const float* __restrict__ wlin,
    const float* __restrict__ blin,
    const int* __restrict__ e1src, const int* __restrict__ e1loc,
    const int* __restrict__ out_deg, const int* __restrict__ counters,
    float* __restrict__ agg1)
{
    __shared__ float xs[16][IN_DIM_K];   // 8 KB
    __shared__ float esc[16];
    __shared__ int   elc[16];
    __shared__ int   esrc_s[16];

    int nE1 = min(counters[2], E1CAP);
    int base = blockIdx.x * 16;
    if (base >= nE1) return;
    int t = threadIdx.x;

    if (t < 16) {
        int ei = base + t;
        if (ei < nE1) {
            int s = e1src[ei];
            esrc_s[t] = s;
            esc[t] = rsqrtf((float)max(out_deg[s], 1));
            elc[t] = e1loc[ei];
        } else {
            esrc_s[t] = -1; esc[t] = 0.f; elc[t] = -1;
        }
    }
    __syncthreads();

    // load 16 x-rows (float4 vectorized, 512 float4 total, 2 per thread)
    #pragma unroll
    for (int i = 0; i < 2; i++) {
        int idx = t + i * 256;
        int e = idx >> 5;          // 32 float4 per 128-float row
        int q = idx & 31;
        int s = esrc_s[e];
        float4 v = make_float4(0.f, 0.f, 0.f, 0.f);
        if (s >= 0) v = ((const float4*)(x + (long long)s * IN_DIM_K))[q];
        ((float4*)xs[e])[q] = v;
    }
    __syncthreads();

    float acc[16];
    #pragma unroll
    for (int e = 0; e < 16; e++) acc[e] = 0.f;

    int j = t;
    for (int k = 0; k < IN_DIM_K; k += 4) {
        float w0 = wlin[(k + 0) * HID_K + j];
        float w1 = wlin[(k + 1) * HID_K + j];
        float w2 = wlin[(k + 2) * HID_K + j];
        float w3 = wlin[(k + 3) * HID_K + j];
        #pragma unroll
        for (int e = 0; e < 16; e++) {
            float4 xv = *(const float4*)&xs[e][k];
            acc[e] = fmaf(xv.x, w0, acc[e]);
            acc[e] = fmaf(xv.y, w1, acc[e]);
            acc[e] = fmaf(xv.z, w2, acc[e]);
            acc[e] = fmaf(xv.w, w3, acc[e]);
        }
    }

    float bj = blin[j];
    #pragma unroll
    for (int e = 0; e < 16; e++) {
        int l = elc[e];
        if (l >= 0) {
            float v = fmaxf(acc[e] + bj, 0.f) * esc[e];
            atomicAdd(&agg1[l * HID_K + j], v);
        }
    }
}

// K5: h1[l] = relu((agg1[l]*in_norm)@w_c0 + b_c0) for l < nF1
__global__ __launch_bounds__(256) void k_h1(
    const float* __restrict__ agg1, const float* __restrict__ wc0,
    const float* __restrict__ bc0,
    const int* __restrict__ nodeOfLoc, const int* __restrict__ in_deg,
    const int* __restrict__ counters, float* __restrict__ h1)
{
    __shared__ float as[16][HID_K];  // 16 KB
    __shared__ float ns[16];

    int nF1 = min(counters[1], F1CAP);
    int base = blockIdx.x * 16;
    if (base >= nF1) return;
    int t = threadIdx.x;

    if (t < 16) {
        int l = base + t;
        ns[t] = (l < nF1) ? rsqrtf((float)max(in_deg[nodeOfLoc[l]], 1)) : 0.f;
    }
    __syncthreads();

    // load+scale 16 agg rows (1024 float4, 4 per thread)
    #pragma unroll
    for (int i = 0; i < 4; i++) {
        int idx = t + i * 256;
        int e = idx >> 6;         // 64 float4 per 256-float row
        int q = idx & 63;
        int l = base + e;
        float4 v = make_float4(0.f, 0.f, 0.f, 0.f);
        if (l < nF1) v = ((const float4*)(agg1 + (long long)l * HID_K))[q];
        float sc = ns[e];
        v.x *= sc; v.y *= sc; v.z *= sc; v.w *= sc;
        ((float4*)as[e])[q] = v;
    }
    __syncthreads();

    float acc[16];
    #pragma unroll
    for (int e = 0; e < 16; e++) acc[e] = 0.f;

    int j = t;
    for (int k = 0; k < HID_K; k += 4) {
        float w0 = wc0[(k + 0) * HID_K + j];
        float w1 = wc0[(k + 1) * HID_K + j];
        float w2 = wc0[(k + 2) * HID_K + j];
        float w3 = wc0[(k + 3) * HID_K + j];
        #pragma unroll
        for (int e = 0; e < 16; e++) {
            float4 av = *(const float4*)&as[e][k];
            acc[e] = fmaf(av.x, w0, acc[e]);
            acc[e] = fmaf(av.y, w1, acc[e]);
            acc[e] = fmaf(av.z, w2, acc[e]);
            acc[e] = fmaf(av.w, w3, acc[e]);
        }
    }

    float bj = bc0[j];
    #pragma unroll
    for (int e = 0; e < 16; e++) {
        int l = base + e;
        if (l < nF1) h1[l * HID_K + j] = fmaxf(acc[e] + bj, 0.f);
    }
}

// K6: agg2[agent] += out_norm[src]*h1[loc[src]]  (one block per level-0 edge)
__global__ __launch_bounds__(256) void k_agg2(
    const int* __restrict__ e0src, const int* __restrict__ e0agent,
    const int* __restrict__ loc, const int* __restrict__ out_deg,
    const float* __restrict__ h1, const int* __restrict__ counters,
    float* __restrict__ agg2)
{
    int nE0 = min(counters[0], E0CAP);
    int e = blockIdx.x;
    if (e >= nE0) return;
    int s = e0src[e];
    int l = loc[s];
    if (l < 0) return;
    float sc = rsqrtf((float)max(out_deg[s], 1));
    int a = e0agent[e];
    int j = threadIdx.x;
    atomicAdd(&agg2[a * HID_K + j], sc * h1[l * HID_K + j]);
}

// K7: per agent: h2 = relu((agg2*in_norm)@w_c1 + b_c1); out = h2@w_emb + b_emb
__global__ __launch_bounds__(256) void k_final(
    const float* __restrict__ agg2, const float* __restrict__ wc1,
    const float* __restrict__ bc1, const float* __restrict__ wemb,
    const float* __restrict__ bemb, const int* __restrict__ in_deg,
    float* __restrict__ out)
{
    __shared__ float a_s[HID_K];
    __shared__ float h2[HID_K];
    int a = blockIdx.x;       // 64 agents
    int t = threadIdx.x;      // 256

    float n = rsqrtf((float)max(in_deg[a * NPG], 1));
    a_s[t] = agg2[a * HID_K + t] * n;
    __syncthreads();

    float acc = 0.f;
    for (int k = 0; k < HID_K; k++)
        acc = fmaf(a_s[k], wc1[k * HID_K + t], acc);
    h2[t] = fmaxf(acc + bc1[t], 0.f);
    __syncthreads();

    if (t < EMB_K) {
        float o = bemb[t];
        for (int k = 0; k < HID_K; k++)
            o = fmaf(h2[k], wemb[k * EMB_K + t], o);
        out[a * EMB_K + t] = o;
    }
}

extern "C" void kernel_launch(void* const* d_in, const int* in_sizes, int n_in,
                              void* d_out, int out_size, void* d_ws, size_t ws_size,
                              hipStream_t stream)
{
    const float* x    = (const float*)d_in[0];
    const int*   src  = (const int*)d_in[1];
    const int*   dst  = (const int*)d_in[2];
    const float* wlin = (const float*)d_in[5];
    const float* blin = (const float*)d_in[6];
    const float* wc0  = (const float*)d_in[7];
    const float* bc0  = (const float*)d_in[8];
    const float* wc1  = (const float*)d_in[9];
    const float* bc1  = (const float*)d_in[10];
    const float* wemb = (const float*)d_in[11];
    const float* bemb = (const float*)d_in[12];
    float* out = (float*)d_out;

    char* ws = (char*)d_ws;
    int*   out_deg   = (int*)(ws + 0);
    int*   in_deg    = (int*)(ws + 524288);
    int*   flag      = (int*)(ws + 1048576);
    int*   counters  = (int*)(ws + 1572864);
    float* agg1      = (float*)(ws + 1573888);
    float* agg2      = (float*)(ws + 5768192);
    int*   loc       = (int*)(ws + 5833728);
    int*   nodeOfLoc = (int*)(ws + 6358016);
    int*   e0src     = (int*)(ws + 6374400);
    int*   e0agent   = (int*)(ws + 6390784);
    int*   e1src     = (int*)(ws + 6407168);
    int*   e1loc     = (int*)(ws + 6931456);
    float* h1        = (float*)(ws + 7455744);

    hipMemsetAsync(d_ws, 0, WS_ZERO_BYTES, stream);

    k_deg_select<<<NEDGE / 256, 256, 0, stream>>>(src, dst, out_deg, in_deg,
                                                  flag, counters, e0src, e0agent);
    k_compact<<<TOTAL_N / 256, 256, 0, stream>>>(flag, loc, nodeOfLoc, counters);
    k_e1_select<<<NEDGE / 256, 256, 0, stream>>>(src, dst, loc, counters, e1src, e1loc);
    k_edge_gemm<<<E1CAP / 16, 256, 0, stream>>>(x, wlin, blin, e1src, e1loc,
                                                out_deg, counters, agg1);
    k_h1<<<F1CAP / 16, 256, 0, stream>>>(agg1, wc0, bc0, nodeOfLoc, in_deg,
                                         counters, h1);
    k_agg2<<<E0CAP, 256, 0, stream>>>(e0src, e0agent, loc, out_deg, h1,
                                      counters, agg2);
    k_final<<<NAGENT, 256, 0, stream>>>(agg2, wc1, bc1, wemb, bemb, in_deg, out);
}

// Round 2
// 512.332 us; speedup vs baseline: 1.8727x; 1.8727x over previous
//
#include <hip/hip_runtime.h>
#include <hip/hip_bf16.h>

#define TOTAL_N   131072
#define NEDGE     4194304
#define NPG       2048
#define IN_DIM_K  128
#define HID_K     256
#define EMB_K     64
#define NAGENT    64

#define E0CAP     4096
#define F1CAP     4096
#define E1CAP     131072

#define SCAN_BLOCKS 2048
#define EPB         2048   // NEDGE / SCAN_BLOCKS
// ---------------- workspace layout (bytes) ----------------
// zeroed every launch:
//   0        : out_deg   int[TOTAL_N]          512K
//   524288   : in_deg    int[TOTAL_N]          512K
//   1048576  : flag      int[TOTAL_N]          512K
//   1572864  : counters  int[256]              1K   ([0]=nE0 [1]=nF1 [2]=nE1)
//   1573888  : agg1      float[F1CAP*HID]      4M
//   5768192  : agg2      float[NAGENT*HID]     64K
//   zero span = [0, 5833728)
// not zeroed (fully written before read):
//   5833728  : loc       int[TOTAL_N]          512K
//   6358016  : nodeOfLoc int[F1CAP]            16K
//   6374400  : e0src     int[E0CAP]            16K
//   6390784  : e0agent   int[E0CAP]            16K
//   6407168  : e1src     int[E1CAP]            512K
//   6931456  : e1loc     int[E1CAP]            512K
//   7455744  : h1        float[F1CAP*HID]      4M
// total = 11650048 bytes (~11.6 MB)

#define WS_ZERO_BYTES 5833728

// K1: full-degree histogram + select edges into agent nodes (block-buffered), mark srcs
__global__ __launch_bounds__(256) void k_deg_select(
    const int* __restrict__ src, const int* __restrict__ dst,
    int* __restrict__ out_deg, int* __restrict__ in_deg,
    int* __restrict__ flag, int* __restrict__ counters,
    int* __restrict__ e0src, int* __restrict__ e0agent)
{
    __shared__ int bs[256], ba[256];
    __shared__ int cnt, gbase;
    if (threadIdx.x == 0) cnt = 0;
    __syncthreads();

    int ebase = blockIdx.x * EPB;
    #pragma unroll
    for (int i = 0; i < EPB / 256; i++) {
        int e = ebase + i * 256 + threadIdx.x;
        int s = src[e], d = dst[e];
        atomicAdd(&out_deg[s], 1);
        atomicAdd(&in_deg[d], 1);
        if ((d & (NPG - 1)) == 0) {
            flag[s] = 1;                       // idempotent race, fine
            int p = atomicAdd(&cnt, 1);        // LDS atomic
            if (p < 256) { bs[p] = s; ba[p] = d >> 11; }
            else {                             // overflow (practically never)
                int gi = atomicAdd(&counters[0], 1);
                if (gi < E0CAP) { e0src[gi] = s; e0agent[gi] = d >> 11; }
            }
        }
    }
    __syncthreads();
    int c = min(cnt, 256);
    if (threadIdx.x == 0) gbase = c ? atomicAdd(&counters[0], c) : 0;
    __syncthreads();
    if (threadIdx.x < c) {
        int i = gbase + threadIdx.x;
        if (i < E0CAP) { e0src[i] = bs[threadIdx.x]; e0agent[i] = ba[threadIdx.x]; }
    }
}

// K2: compact frontier F1 (block-buffered prefix, one global atomic per block)
__global__ __launch_bounds__(256) void k_compact(
    const int* __restrict__ flag, int* __restrict__ loc,
    int* __restrict__ nodeOfLoc, int* __restrict__ counters)
{
    __shared__ int cnt, gbase;
    if (threadIdx.x == 0) cnt = 0;
    __syncthreads();
    int v = blockIdx.x * 256 + threadIdx.x;
    int p = -1;
    if (flag[v]) p = atomicAdd(&cnt, 1);       // LDS atomic
    __syncthreads();
    if (threadIdx.x == 0) gbase = cnt ? atomicAdd(&counters[1], cnt) : 0;
    __syncthreads();
    int l = -1;
    if (p >= 0) {
        int id = gbase + p;
        if (id < F1CAP) { l = id; nodeOfLoc[id] = v; }
    }
    loc[v] = l;
}

// K3: select edges whose dst is in F1 — block-buffered compaction in LDS
__global__ __launch_bounds__(256) void k_e1_select(
    const int* __restrict__ src, const int* __restrict__ dst,
    const int* __restrict__ loc, int* __restrict__ counters,
    int* __restrict__ e1src, int* __restrict__ e1loc)
{
    __shared__ int bsrc[EPB];   // 8 KB
    __shared__ int bloc[EPB];   // 8 KB
    __shared__ int cnt, gbase;
    if (threadIdx.x == 0) cnt = 0;
    __syncthreads();

    int ebase = blockIdx.x * EPB;
    #pragma unroll
    for (int i = 0; i < EPB / 256; i++) {
        int e = ebase + i * 256 + threadIdx.x;
        int l = loc[dst[e]];
        if (l >= 0) {
            int p = atomicAdd(&cnt, 1);        // LDS atomic, capacity EPB is a hard bound
            bsrc[p] = src[e];
            bloc[p] = l;
        }
    }
    __syncthreads();
    if (threadIdx.x == 0) gbase = cnt ? atomicAdd(&counters[2], cnt) : 0;
    __syncthreads();
    for (int p = threadIdx.x; p < cnt; p += 256) {
        int i = gbase + p;
        if (i < E1CAP) { e1src[i] = bsrc[p]; e1loc[i] = bloc[p]; }
    }
}

// K4: per selected edge: h0 = relu(x[src]@w_lin + b_lin); agg1[loc[dst]] += out_norm[src]*h0
// 16 edges per 256-thread block; thread j owns output column j.
__global__ __launch_bounds__(256) void k_edge_gemm(
    const float* __restrict__ x, const float* __restrict__ wlin,
    const float* __restrict__ blin,
    const int* __restrict__ e1src, const int* __restrict__ e1loc,
    const int* __restrict__ out_deg, const int* __restrict__ counters,
    float* __restrict__ agg1)
{
    __shared__ float xs[16][IN_DIM_K];   // 8 KB
    __shared__ float esc[16];
    __shared__ int   elc[16];
    __shared__ int   esrc_s[16];

    int nE1 = min(counters[2], E1CAP);
    int base = blockIdx.x * 16;
    if (base >= nE1) return;
    int t = threadIdx.x;

    if (t < 16) {
        int ei = base + t;
        if (ei < nE1) {
            int s = e1src[ei];
            esrc_s[t] = s;
            esc[t] = rsqrtf((float)max(out_deg[s], 1));
            elc[t] = e1loc[ei];
        } else {
            esrc_s[t] = -1; esc[t] = 0.f; elc[t] = -1;
        }
    }
    __syncthreads();

    #pragma unroll
    for (int i = 0; i < 2; i++) {
        int idx = t + i * 256;
        int e = idx >> 5;          // 32 float4 per 128-float row
        int q = idx & 31;
        int s = esrc_s[e];
        float4 v = make_float4(0.f, 0.f, 0.f, 0.f);
        if (s >= 0) v = ((const float4*)(x + (long long)s * IN_DIM_K))[q];
        ((float4*)xs[e])[q] = v;
    }
    __syncthreads();

    float acc[16];
    #pragma unroll
    for (int e = 0; e < 16; e++) acc[e] = 0.f;

    int j = t;
    for (int k = 0; k < IN_DIM_K; k += 4) {
        float w0 = wlin[(k + 0) * HID_K + j];
        float w1 = wlin[(k + 1) * HID_K + j];
        float w2 = wlin[(k + 2) * HID_K + j];
        float w3 = wlin[(k + 3) * HID_K + j];
        #pragma unroll
        for (int e = 0; e < 16; e++) {
            float4 xv = *(const float4*)&xs[e][k];
            acc[e] = fmaf(xv.x, w0, acc[e]);
            acc[e] = fmaf(xv.y, w1, acc[e]);
            acc[e] = fmaf(xv.z, w2, acc[e]);
            acc[e] = fmaf(xv.w, w3, acc[e]);
        }
    }

    float bj = blin[j];
    #pragma unroll
    for (int e = 0; e < 16; e++) {
        int l = elc[e];
        if (l >= 0) {
            float v = fmaxf(acc[e] + bj, 0.f) * esc[e];
            atomicAdd(&agg1[l * HID_K + j], v);
        }
    }
}

// K5: h1[l] = relu((agg1[l]*in_norm)@w_c0 + b_c0) for l < nF1
__global__ __launch_bounds__(256) void k_h1(
    const float* __restrict__ agg1, const float* __restrict__ wc0,
    const float* __restrict__ bc0,
    const int* __restrict__ nodeOfLoc, const int* __restrict__ in_deg,
    const int* __restrict__ counters, float* __restrict__ h1)
{
    __shared__ float as[16][HID_K];  // 16 KB
    __shared__ float ns[16];

    int nF1 = min(counters[1], F1CAP);
    int base = blockIdx.x * 16;
    if (base >= nF1) return;
    int t = threadIdx.x;

    if (t < 16) {
        int l = base + t;
        ns[t] = (l < nF1) ? rsqrtf((float)max(in_deg[nodeOfLoc[l]], 1)) : 0.f;
    }
    __syncthreads();

    #pragma unroll
    for (int i = 0; i < 4; i++) {
        int idx = t + i * 256;
        int e = idx >> 6;         // 64 float4 per 256-float row
        int q = idx & 63;
        int l = base + e;
        float4 v = make_float4(0.f, 0.f, 0.f, 0.f);
        if (l < nF1) v = ((const float4*)(agg1 + (long long)l * HID_K))[q];
        float sc = ns[e];
        v.x *= sc; v.y *= sc; v.z *= sc; v.w *= sc;
        ((float4*)as[e])[q] = v;
    }
    __syncthreads();

    float acc[16];
    #pragma unroll
    for (int e = 0; e < 16; e++) acc[e] = 0.f;

    int j = t;
    for (int k = 0; k < HID_K; k += 4) {
        float w0 = wc0[(k + 0) * HID_K + j];
        float w1 = wc0[(k + 1) * HID_K + j];
        float w2 = wc0[(k + 2) * HID_K + j];
        float w3 = wc0[(k + 3) * HID_K + j];
        #pragma unroll
        for (int e = 0; e < 16; e++) {
            float4 av = *(const float4*)&as[e][k];
            acc[e] = fmaf(av.x, w0, acc[e]);
            acc[e] = fmaf(av.y, w1, acc[e]);
            acc[e] = fmaf(av.z, w2, acc[e]);
            acc[e] = fmaf(av.w, w3, acc[e]);
        }
    }

    float bj = bc0[j];
    #pragma unroll
    for (int e = 0; e < 16; e++) {
        int l = base + e;
        if (l < nF1) h1[l * HID_K + j] = fmaxf(acc[e] + bj, 0.f);
    }
}

// K6: agg2[agent] += out_norm[src]*h1[loc[src]]  (one block per level-0 edge)
__global__ __launch_bounds__(256) void k_agg2(
    const int* __restrict__ e0src, const int* __restrict__ e0agent,
    const int* __restrict__ loc, const int* __restrict__ out_deg,
    const float* __restrict__ h1, const int* __restrict__ counters,
    float* __restrict__ agg2)
{
    int nE0 = min(counters[0], E0CAP);
    int e = blockIdx.x;
    if (e >= nE0) return;
    int s = e0src[e];
    int l = loc[s];
    if (l < 0) return;
    float sc = rsqrtf((float)max(out_deg[s], 1));
    int a = e0agent[e];
    int j = threadIdx.x;
    atomicAdd(&agg2[a * HID_K + j], sc * h1[l * HID_K + j]);
}

// K7: per agent: h2 = relu((agg2*in_norm)@w_c1 + b_c1); out = h2@w_emb + b_emb
__global__ __launch_bounds__(256) void k_final(
    const float* __restrict__ agg2, const float* __restrict__ wc1,
    const float* __restrict__ bc1, const float* __restrict__ wemb,
    const float* __restrict__ bemb, const int* __restrict__ in_deg,
    float* __restrict__ out)
{
    __shared__ float a_s[HID_K];
    __shared__ float h2[HID_K];
    int a = blockIdx.x;       // 64 agents
    int t = threadIdx.x;      // 256

    float n = rsqrtf((float)max(in_deg[a * NPG], 1));
    a_s[t] = agg2[a * HID_K + t] * n;
    __syncthreads();

    float acc = 0.f;
    for (int k = 0; k < HID_K; k++)
        acc = fmaf(a_s[k], wc1[k * HID_K + t], acc);
    h2[t] = fmaxf(acc + bc1[t], 0.f);
    __syncthreads();

    if (t < EMB_K) {
        float o = bemb[t];
        for (int k = 0; k < HID_K; k++)
            o = fmaf(h2[k], wemb[k * EMB_K + t], o);
        out[a * EMB_K + t] = o;
    }
}

extern "C" void kernel_launch(void* const* d_in, const int* in_sizes, int n_in,
                              void* d_out, int out_size, void* d_ws, size_t ws_size,
                              hipStream_t stream)
{
    const float* x    = (const float*)d_in[0];
    const int*   src  = (const int*)d_in[1];
    const int*   dst  = (const int*)d_in[2];
    const float* wlin = (const float*)d_in[5];
    const float* blin = (const float*)d_in[6];
    const float* wc0  = (const float*)d_in[7];
    const float* bc0  = (const float*)d_in[8];
    const float* wc1  = (const float*)d_in[9];
    const float* bc1  = (const float*)d_in[10];
    const float* wemb = (const float*)d_in[11];
    const float* bemb = (const float*)d_in[12];
    float* out = (float*)d_out;

    char* ws = (char*)d_ws;
    int*   out_deg   = (int*)(ws + 0);
    int*   in_deg    = (int*)(ws + 524288);
    int*   flag      = (int*)(ws + 1048576);
    int*   counters  = (int*)(ws + 1572864);
    float* agg1      = (float*)(ws + 1573888);
    float* agg2      = (float*)(ws + 5768192);
    int*   loc       = (int*)(ws + 5833728);
    int*   nodeOfLoc = (int*)(ws + 6358016);
    int*   e0src     = (int*)(ws + 6374400);
    int*   e0agent   = (int*)(ws + 6390784);
    int*   e1src     = (int*)(ws + 6407168);
    int*   e1loc     = (int*)(ws + 6931456);
    float* h1        = (float*)(ws + 7455744);

    hipMemsetAsync(d_ws, 0, WS_ZERO_BYTES, stream);

    k_deg_select<<<SCAN_BLOCKS, 256, 0, stream>>>(src, dst, out_deg, in_deg,
                                                  flag, counters, e0src, e0agent);
    k_compact<<<TOTAL_N / 256, 256, 0, stream>>>(flag, loc, nodeOfLoc, counters);
    k_e1_select<<<SCAN_BLOCKS, 256, 0, stream>>>(src, dst, loc, counters, e1src, e1loc);
    k_edge_gemm<<<E1CAP / 16, 256, 0, stream>>>(x, wlin, blin, e1src, e1loc,
                                                out_deg, counters, agg1);
    k_h1<<<F1CAP / 16, 256, 0, stream>>>(agg1, wc0, bc0, nodeOfLoc, in_deg,
                                         counters, h1);
    k_agg2<<<E0CAP, 256, 0, stream>>>(e0src, e0agent, loc, out_deg, h1,
                                      counters, agg2);
    k_final<<<NAGENT, 256, 0, stream>>>(agg2, wc1, bc1, wemb, bemb, in_deg, out);
}

// Round 3
// 220.225 us; speedup vs baseline: 4.3566x; 2.3264x over previous
//
#include <hip/hip_runtime.h>
#include <hip/hip_bf16.h>

#define TOTAL_N   131072
#define NEDGE     4194304
#define NPG       2048
#define IN_DIM_K  128
#define HID_K     256
#define EMB_K     64
#define NAGENT    64

#define E0CAP     4096
#define F1CAP     4096
#define E1CAP     131072

#define G1        128                 // k_outdeg_e0 blocks
#define EPB1      (NEDGE / G1)        // 32768 edges per block
#define HWORDS    (TOTAL_N / 8)       // 16384 nibble-packed u32 words

#define SCAN_BLOCKS 2048
#define EPB         2048              // NEDGE / SCAN_BLOCKS

// ---------------- workspace layout (bytes) ----------------
// zeroed every launch [0, 655360):
//   0        counters  int[256]        1K   ([0]=nE0 [1]=nF1 [2]=nE1)
//   1024     inF1      int[F1CAP]      16K  (in-degree of F1 nodes, by compact id)
//   17408    inAgent   int[64]         256B (in-degree of agent nodes)
//   65536    flag      int[TOTAL_N]    512K
//   589824   agg2      float[64*HID]   64K
// not zeroed (fully written before read):
//   655360   loc       int[TOTAL_N]    512K
//   1179648  e0src     int[E0CAP]      16K
//   1196032  e0agent   int[E0CAP]      16K
//   1212416  e1src     int[E1CAP]      512K
//   1736704  e1loc     int[E1CAP]      512K
//   2260992  out_deg   u32[TOTAL_N]    512K
//   2785280  partial   u32[G1*HWORDS]  8M    (dead after reduce; region reused:)
//     2785280  agg1    float[F1CAP*HID] 4M   (re-zeroed by memset after reduce)
//     6979584  h1      float[F1CAP*HID] 4M   (fully written rows < nF1)
// total = 11173888 (~10.7 MB)

#define ZERO_SPAN 655360

// K1: out-degree histogram (nibble-packed LDS, zero global atomics) + e0 select
__global__ __launch_bounds__(1024) void k_outdeg_e0(
    const int* __restrict__ src, const int* __restrict__ dst,
    unsigned int* __restrict__ partial,
    int* __restrict__ flag, int* __restrict__ counters,
    int* __restrict__ e0src, int* __restrict__ e0agent,
    int* __restrict__ inAgent)
{
    __shared__ unsigned int hist[HWORDS];   // 64 KB, 8 nodes/word, u4 counters
    __shared__ int bs[1024], ba[1024];      // 8 KB e0 staging
    __shared__ int cnt, gbase;
    int t = threadIdx.x;
    for (int i = t; i < HWORDS; i += 1024) hist[i] = 0u;
    if (t == 0) cnt = 0;
    __syncthreads();

    int ebase = blockIdx.x * EPB1;
    #pragma unroll 4
    for (int i = 0; i < EPB1 / 1024; i++) {
        int e = ebase + i * 1024 + t;
        int s = src[e], d = dst[e];
        atomicAdd(&hist[s >> 3], 1u << ((s & 7) * 4));   // LDS atomic
        if ((d & (NPG - 1)) == 0) {
            flag[s] = 1;                                 // idempotent race
            int p = atomicAdd(&cnt, 1);
            if (p < 1024) { bs[p] = s; ba[p] = d >> 11; }
            else {  // practically impossible overflow path
                int gi = atomicAdd(&counters[0], 1);
                if (gi < E0CAP) { e0src[gi] = s; e0agent[gi] = d >> 11; }
                atomicAdd(&inAgent[d >> 11], 1);
            }
        }
    }
    __syncthreads();
    int c = min(cnt, 1024);
    if (t == 0) gbase = c ? atomicAdd(&counters[0], c) : 0;
    __syncthreads();
    if (t < c) {
        int i = gbase + t;
        if (i < E0CAP) { e0src[i] = bs[t]; e0agent[i] = ba[t]; }
        atomicAdd(&inAgent[ba[t]], 1);
    }
    unsigned int* pout = partial + blockIdx.x * HWORDS;
    for (int i = t; i < HWORDS; i += 1024) pout[i] = hist[i];
}

// K1b: reduce nibble partials -> u32 out_deg. SWAR: nibbles -> u8 lanes (max deg ~77 < 256)
__global__ __launch_bounds__(256) void k_outdeg_reduce(
    const unsigned int* __restrict__ partial, unsigned int* __restrict__ out_deg)
{
    int w = blockIdx.x * 256 + threadIdx.x;   // 16384 words
    unsigned int accE = 0, accO = 0;
    #pragma unroll 8
    for (int g = 0; g < G1; g++) {
        unsigned int v = partial[g * HWORDS + w];
        accE += v & 0x0F0F0F0Fu;          // nodes 8w+0,2,4,6 in u8 lanes
        accO += (v >> 4) & 0x0F0F0F0Fu;   // nodes 8w+1,3,5,7
    }
    uint4 lo = make_uint4(accE & 255u, accO & 255u, (accE >> 8) & 255u, (accO >> 8) & 255u);
    uint4 hi = make_uint4((accE >> 16) & 255u, (accO >> 16) & 255u, (accE >> 24) & 255u, (accO >> 24) & 255u);
    ((uint4*)(out_deg + 8 * w))[0] = lo;
    ((uint4*)(out_deg + 8 * w))[1] = hi;
}

// K2: compact frontier F1 (one global atomic per block)
__global__ __launch_bounds__(256) void k_compact(
    const int* __restrict__ flag, int* __restrict__ loc,
    int* __restrict__ counters)
{
    __shared__ int cnt, gbase;
    if (threadIdx.x == 0) cnt = 0;
    __syncthreads();
    int v = blockIdx.x * 256 + threadIdx.x;
    int p = -1;
    if (flag[v]) p = atomicAdd(&cnt, 1);
    __syncthreads();
    if (threadIdx.x == 0) gbase = cnt ? atomicAdd(&counters[1], cnt) : 0;
    __syncthreads();
    int l = -1;
    if (p >= 0) {
        int id = gbase + p;
        if (id < F1CAP) l = id;
    }
    loc[v] = l;
}

// K3: select edges with dst in F1 (block-buffered) + inF1 in-degree histogram
__global__ __launch_bounds__(256) void k_e1_select(
    const int* __restrict__ src, const int* __restrict__ dst,
    const int* __restrict__ loc, int* __restrict__ counters,
    int* __restrict__ e1src, int* __restrict__ e1loc,
    int* __restrict__ inF1)
{
    __shared__ int bsrc[EPB];   // 8 KB
    __shared__ int bloc[EPB];   // 8 KB
    __shared__ int cnt, gbase;
    if (threadIdx.x == 0) cnt = 0;
    __syncthreads();

    int ebase = blockIdx.x * EPB;
    #pragma unroll
    for (int i = 0; i < EPB / 256; i++) {
        int e = ebase + i * 256 + threadIdx.x;
        int l = loc[dst[e]];
        if (l >= 0) {
            atomicAdd(&inF1[l], 1);            // ~65K atomics on 16KB L2 array
            int p = atomicAdd(&cnt, 1);        // LDS
            bsrc[p] = src[e];
            bloc[p] = l;
        }
    }
    __syncthreads();
    if (threadIdx.x == 0) gbase = cnt ? atomicAdd(&counters[2], cnt) : 0;
    __syncthreads();
    for (int p = threadIdx.x; p < cnt; p += 256) {
        int i = gbase + p;
        if (i < E1CAP) { e1src[i] = bsrc[p]; e1loc[i] = bloc[p]; }
    }
}

// K4: per selected edge: h0 = relu(x[src]@w_lin + b_lin); agg1[l] += out_norm[src]*h0
__global__ __launch_bounds__(256) void k_edge_gemm(
    const float* __restrict__ x, const float* __restrict__ wlin,
    const float* __restrict__ blin,
    const int* __restrict__ e1src, const int* __restrict__ e1loc,
    const unsigned int* __restrict__ out_deg, const int* __restrict__ counters,
    float* __restrict__ agg1)
{
    __shared__ float xs[16][IN_DIM_K];   // 8 KB
    __shared__ float esc[16];
    __shared__ int   elc[16];
    __shared__ int   esrc_s[16];

    int nE1 = min(counters[2], E1CAP);
    int base = blockIdx.x * 16;
    if (base >= nE1) return;
    int t = threadIdx.x;

    if (t < 16) {
        int ei = base + t;
        if (ei < nE1) {
            int s = e1src[ei];
            esrc_s[t] = s;
            esc[t] = rsqrtf((float)max((int)out_deg[s], 1));
            elc[t] = e1loc[ei];
        } else {
            esrc_s[t] = -1; esc[t] = 0.f; elc[t] = -1;
        }
    }
    __syncthreads();

    #pragma unroll
    for (int i = 0; i < 2; i++) {
        int idx = t + i * 256;
        int e = idx >> 5;
        int q = idx & 31;
        int s = esrc_s[e];
        float4 v = make_float4(0.f, 0.f, 0.f, 0.f);
        if (s >= 0) v = ((const float4*)(x + (long long)s * IN_DIM_K))[q];
        ((float4*)xs[e])[q] = v;
    }
    __syncthreads();

    float acc[16];
    #pragma unroll
    for (int e = 0; e < 16; e++) acc[e] = 0.f;

    int j = t;
    for (int k = 0; k < IN_DIM_K; k += 4) {
        float w0 = wlin[(k + 0) * HID_K + j];
        float w1 = wlin[(k + 1) * HID_K + j];
        float w2 = wlin[(k + 2) * HID_K + j];
        float w3 = wlin[(k + 3) * HID_K + j];
        #pragma unroll
        for (int e = 0; e < 16; e++) {
            float4 xv = *(const float4*)&xs[e][k];
            acc[e] = fmaf(xv.x, w0, acc[e]);
            acc[e] = fmaf(xv.y, w1, acc[e]);
            acc[e] = fmaf(xv.z, w2, acc[e]);
            acc[e] = fmaf(xv.w, w3, acc[e]);
        }
    }

    float bj = blin[j];
    #pragma unroll
    for (int e = 0; e < 16; e++) {
        int l = elc[e];
        if (l >= 0) {
            float v = fmaxf(acc[e] + bj, 0.f) * esc[e];
            atomicAdd(&agg1[l * HID_K + j], v);
        }
    }
}

// K5: h1[l] = relu((agg1[l]*in_norm)@w_c0 + b_c0), in_norm from inF1
__global__ __launch_bounds__(256) void k_h1(
    const float* __restrict__ agg1, const float* __restrict__ wc0,
    const float* __restrict__ bc0,
    const int* __restrict__ inF1,
    const int* __restrict__ counters, float* __restrict__ h1)
{
    __shared__ float as[16][HID_K];  // 16 KB
    __shared__ float ns[16];

    int nF1 = min(counters[1], F1CAP);
    int base = blockIdx.x * 16;
    if (base >= nF1) return;
    int t = threadIdx.x;

    if (t < 16) {
        int l = base + t;
        ns[t] = (l < nF1) ? rsqrtf((float)max(inF1[l], 1)) : 0.f;
    }
    __syncthreads();

    #pragma unroll
    for (int i = 0; i < 4; i++) {
        int idx = t + i * 256;
        int e = idx >> 6;
        int q = idx & 63;
        int l = base + e;
        float4 v = make_float4(0.f, 0.f, 0.f, 0.f);
        if (l < nF1) v = ((const float4*)(agg1 + (long long)l * HID_K))[q];
        float sc = ns[e];
        v.x *= sc; v.y *= sc; v.z *= sc; v.w *= sc;
        ((float4*)as[e])[q] = v;
    }
    __syncthreads();

    float acc[16];
    #pragma unroll
    for (int e = 0; e < 16; e++) acc[e] = 0.f;

    int j = t;
    for (int k = 0; k < HID_K; k += 4) {
        float w0 = wc0[(k + 0) * HID_K + j];
        float w1 = wc0[(k + 1) * HID_K + j];
        float w2 = wc0[(k + 2) * HID_K + j];
        float w3 = wc0[(k + 3) * HID_K + j];
        #pragma unroll
        for (int e = 0; e < 16; e++) {
            float4 av = *(const float4*)&as[e][k];
            acc[e] = fmaf(av.x, w0, acc[e]);
            acc[e] = fmaf(av.y, w1, acc[e]);
            acc[e] = fmaf(av.z, w2, acc[e]);
            acc[e] = fmaf(av.w, w3, acc[e]);
        }
    }

    float bj = bc0[j];
    #pragma unroll
    for (int e = 0; e < 16; e++) {
        int l = base + e;
        if (l < nF1) h1[l * HID_K + j] = fmaxf(acc[e] + bj, 0.f);
    }
}

// K6: agg2[agent] += out_norm[src]*h1[loc[src]]
__global__ __launch_bounds__(256) void k_agg2(
    const int* __restrict__ e0src, const int* __restrict__ e0agent,
    const int* __restrict__ loc, const unsigned int* __restrict__ out_deg,
    const float* __restrict__ h1, const int* __restrict__ counters,
    float* __restrict__ agg2)
{
    int nE0 = min(counters[0], E0CAP);
    int e = blockIdx.x;
    if (e >= nE0) return;
    int s = e0src[e];
    int l = loc[s];
    if (l < 0) return;
    float sc = rsqrtf((float)max((int)out_deg[s], 1));
    int a = e0agent[e];
    int j = threadIdx.x;
    atomicAdd(&agg2[a * HID_K + j], sc * h1[l * HID_K + j]);
}

// K7: per agent: h2 = relu((agg2*in_norm)@w_c1 + b_c1); out = h2@w_emb + b_emb
__global__ __launch_bounds__(256) void k_final(
    const float* __restrict__ agg2, const float* __restrict__ wc1,
    const float* __restrict__ bc1, const float* __restrict__ wemb,
    const float* __restrict__ bemb, const int* __restrict__ inAgent,
    float* __restrict__ out)
{
    __shared__ float a_s[HID_K];
    __shared__ float h2[HID_K];
    int a = blockIdx.x;
    int t = threadIdx.x;

    float n = rsqrtf((float)max(inAgent[a], 1));
    a_s[t] = agg2[a * HID_K + t] * n;
    __syncthreads();

    float acc = 0.f;
    for (int k = 0; k < HID_K; k++)
        acc = fmaf(a_s[k], wc1[k * HID_K + t], acc);
    h2[t] = fmaxf(acc + bc1[t], 0.f);
    __syncthreads();

    if (t < EMB_K) {
        float o = bemb[t];
        for (int k = 0; k < HID_K; k++)
            o = fmaf(h2[k], wemb[k * EMB_K + t], o);
        out[a * EMB_K + t] = o;
    }
}

extern "C" void kernel_launch(void* const* d_in, const int* in_sizes, int n_in,
                              void* d_out, int out_size, void* d_ws, size_t ws_size,
                              hipStream_t stream)
{
    const float* x    = (const float*)d_in[0];
    const int*   src  = (const int*)d_in[1];
    const int*   dst  = (const int*)d_in[2];
    const float* wlin = (const float*)d_in[5];
    const float* blin = (const float*)d_in[6];
    const float* wc0  = (const float*)d_in[7];
    const float* bc0  = (const float*)d_in[8];
    const float* wc1  = (const float*)d_in[9];
    const float* bc1  = (const float*)d_in[10];
    const float* wemb = (const float*)d_in[11];
    const float* bemb = (const float*)d_in[12];
    float* out = (float*)d_out;

    char* ws = (char*)d_ws;
    int*          counters = (int*)(ws + 0);
    int*          inF1     = (int*)(ws + 1024);
    int*          inAgent  = (int*)(ws + 17408);
    int*          flag     = (int*)(ws + 65536);
    float*        agg2     = (float*)(ws + 589824);
    int*          loc      = (int*)(ws + 655360);
    int*          e0src    = (int*)(ws + 1179648);
    int*          e0agent  = (int*)(ws + 1196032);
    int*          e1src    = (int*)(ws + 1212416);
    int*          e1loc    = (int*)(ws + 1736704);
    unsigned int* out_deg  = (unsigned int*)(ws + 2260992);
    unsigned int* partial  = (unsigned int*)(ws + 2785280);   // 8 MB, dead after reduce
    float*        agg1     = (float*)(ws + 2785280);          // reuses partial[0:4M]
    float*        h1       = (float*)(ws + 6979584);          // reuses partial[4M:8M]

    hipMemsetAsync(ws, 0, ZERO_SPAN, stream);

    k_outdeg_e0<<<G1, 1024, 0, stream>>>(src, dst, partial, flag, counters,
                                         e0src, e0agent, inAgent);
    k_outdeg_reduce<<<HWORDS / 256, 256, 0, stream>>>(partial, out_deg);
    hipMemsetAsync(agg1, 0, (size_t)F1CAP * HID_K * 4, stream);  // partial now dead

    k_compact<<<TOTAL_N / 256, 256, 0, stream>>>(flag, loc, counters);
    k_e1_select<<<SCAN_BLOCKS, 256, 0, stream>>>(src, dst, loc, counters,
                                                 e1src, e1loc, inF1);
    k_edge_gemm<<<E1CAP / 16, 256, 0, stream>>>(x, wlin, blin, e1src, e1loc,
                                                out_deg, counters, agg1);
    k_h1<<<F1CAP / 16, 256, 0, stream>>>(agg1, wc0, bc0, inF1, counters, h1);
    k_agg2<<<E0CAP, 256, 0, stream>>>(e0src, e0agent, loc, out_deg, h1,
                                      counters, agg2);
    k_final<<<NAGENT, 256, 0, stream>>>(agg2, wc1, bc1, wemb, bemb, inAgent, out);
}

// Round 4
// 163.635 us; speedup vs baseline: 5.8632x; 1.3458x over previous
//
#include <hip/hip_runtime.h>
#include <hip/hip_bf16.h>

#define TOTAL_N   131072
#define NEDGE     4194304
#define NPG       2048
#define IN_DIM_K  128
#define HID_K     256
#define EMB_K     64
#define NAGENT    64

#define E0CAP     4096
#define F1CAP     4096
#define E1CAP     98304      // 1.5x expected nE1 (~65K)

#define G1        128                 // k_outdeg_e0 blocks
#define EPB1      (NEDGE / G1)        // 32768 edges per block
#define HWORDS    (TOTAL_N / 8)       // 16384 nibble-packed u32 words

#define SCAN_BLOCKS 2048
#define EPB         2048              // NEDGE / SCAN_BLOCKS

// ---------------- workspace layout (bytes) ----------------
// zeroed every launch [0, 655360):
//   0        counters  int[256]        ([0]=nE0 [1]=nF1 [2]=nE1)
//   1024     inF1      int[F1CAP]      16K
//   17408    inAgent   int[64]
//   65536    flag      int[TOTAL_N]    512K   (dead after k_compact; region reused:)
//     65536    es_pack int[E1CAP]      384K   (written by k_scatter)
//   589824   agg2      float[64*HID]   64K
// not zeroed (fully written before read):
//   655360   loc       int[TOTAL_N]    512K
//   1179648  e0src     int[E0CAP]      16K
//   1196032  e0agent   int[E0CAP]      16K
//   1212416  e1src     int[E1CAP]      384K
//   1605632  e1loc     int[E1CAP]      384K
//   1998848  out_deg   u32[TOTAL_N]    512K
//   2523136  wswz      u16[32768]      64K    (wlin in MFMA frag order, bf16)
//   2588672  cursor    int[F1CAP]      16K    (fully written by k_scan)
//   2621440  partial   u32[G1*HWORDS]  8M     (dead after reduce; reused:)
//     2621440  agg1    float[F1CAP*HID] 4M    (memset after reduce)
//     6815744  h1      float[F1CAP*HID] 4M
// total = 11010048 (~10.5 MB)

#define ZERO_SPAN 655360

typedef float f32x4 __attribute__((ext_vector_type(4)));
typedef short bf16x8 __attribute__((ext_vector_type(8)));

__device__ inline unsigned short f2bf(float f) {   // RNE f32->bf16
    unsigned int u = __float_as_uint(f);
    return (unsigned short)((u + 0x7FFFu + ((u >> 16) & 1u)) >> 16);
}

// K0: pre-swizzle wlin into bf16 MFMA B-fragment order:
// wswz[((kt*16+ct)*64 + lane)*8 + i] = bf16(wlin[kt*32 + 8*(lane>>4) + i][ct*16 + (lane&15)])
__global__ __launch_bounds__(256) void k_wprep(const float* __restrict__ wlin,
                                               unsigned short* __restrict__ wswz)
{
    int t = blockIdx.x * 256 + threadIdx.x;   // 4096 = 4 kt * 16 ct * 64 lanes
    int lane = t & 63;
    int ct = (t >> 6) & 15;
    int kt = t >> 10;
    int colbase = ct * 16 + (lane & 15);
    int kbase = kt * 32 + (lane >> 4) * 8;
    unsigned short o[8];
    #pragma unroll
    for (int i = 0; i < 8; i++) o[i] = f2bf(wlin[(kbase + i) * HID_K + colbase]);
    *(ushort4*)(wswz + t * 8)     = make_ushort4(o[0], o[1], o[2], o[3]);
    *(ushort4*)(wswz + t * 8 + 4) = make_ushort4(o[4], o[5], o[6], o[7]);
}

// K1: out-degree histogram (nibble-packed LDS) + e0 select
__global__ __launch_bounds__(1024) void k_outdeg_e0(
    const int* __restrict__ src, const int* __restrict__ dst,
    unsigned int* __restrict__ partial,
    int* __restrict__ flag, int* __restrict__ counters,
    int* __restrict__ e0src, int* __restrict__ e0agent,
    int* __restrict__ inAgent)
{
    __shared__ unsigned int hist[HWORDS];   // 64 KB
    __shared__ int bs[1024], ba[1024];
    __shared__ int cnt, gbase;
    int t = threadIdx.x;
    for (int i = t; i < HWORDS; i += 1024) hist[i] = 0u;
    if (t == 0) cnt = 0;
    __syncthreads();

    int ebase = blockIdx.x * EPB1;
    #pragma unroll 4
    for (int i = 0; i < EPB1 / 1024; i++) {
        int e = ebase + i * 1024 + t;
        int s = src[e], d = dst[e];
        atomicAdd(&hist[s >> 3], 1u << ((s & 7) * 4));
        if ((d & (NPG - 1)) == 0) {
            flag[s] = 1;
            int p = atomicAdd(&cnt, 1);
            if (p < 1024) { bs[p] = s; ba[p] = d >> 11; }
            else {
                int gi = atomicAdd(&counters[0], 1);
                if (gi < E0CAP) { e0src[gi] = s; e0agent[gi] = d >> 11; }
                atomicAdd(&inAgent[d >> 11], 1);
            }
        }
    }
    __syncthreads();
    int c = min(cnt, 1024);
    if (t == 0) gbase = c ? atomicAdd(&counters[0], c) : 0;
    __syncthreads();
    if (t < c) {
        int i = gbase + t;
        if (i < E0CAP) { e0src[i] = bs[t]; e0agent[i] = ba[t]; }
        atomicAdd(&inAgent[ba[t]], 1);
    }
    unsigned int* pout = partial + blockIdx.x * HWORDS;
    for (int i = t; i < HWORDS; i += 1024) pout[i] = hist[i];
}

// K1b: reduce nibble partials -> u32 out_deg (SWAR u8 lanes, max deg < 256)
__global__ __launch_bounds__(256) void k_outdeg_reduce(
    const unsigned int* __restrict__ partial, unsigned int* __restrict__ out_deg)
{
    int w = blockIdx.x * 256 + threadIdx.x;
    unsigned int accE = 0, accO = 0;
    #pragma unroll 8
    for (int g = 0; g < G1; g++) {
        unsigned int v = partial[g * HWORDS + w];
        accE += v & 0x0F0F0F0Fu;
        accO += (v >> 4) & 0x0F0F0F0Fu;
    }
    uint4 lo = make_uint4(accE & 255u, accO & 255u, (accE >> 8) & 255u, (accO >> 8) & 255u);
    uint4 hi = make_uint4((accE >> 16) & 255u, (accO >> 16) & 255u, (accE >> 24) & 255u, (accO >> 24) & 255u);
    ((uint4*)(out_deg + 8 * w))[0] = lo;
    ((uint4*)(out_deg + 8 * w))[1] = hi;
}

// K2: compact frontier F1
__global__ __launch_bounds__(256) void k_compact(
    const int* __restrict__ flag, int* __restrict__ loc,
    int* __restrict__ counters)
{
    __shared__ int cnt, gbase;
    if (threadIdx.x == 0) cnt = 0;
    __syncthreads();
    int v = blockIdx.x * 256 + threadIdx.x;
    int p = -1;
    if (flag[v]) p = atomicAdd(&cnt, 1);
    __syncthreads();
    if (threadIdx.x == 0) gbase = cnt ? atomicAdd(&counters[1], cnt) : 0;
    __syncthreads();
    int l = -1;
    if (p >= 0) {
        int id = gbase + p;
        if (id < F1CAP) l = id;
    }
    loc[v] = l;
}

// K3: select edges with dst in F1 (block-buffered) + inF1 histogram
__global__ __launch_bounds__(256) void k_e1_select(
    const int* __restrict__ src, const int* __restrict__ dst,
    const int* __restrict__ loc, int* __restrict__ counters,
    int* __restrict__ e1src, int* __restrict__ e1loc,
    int* __restrict__ inF1)
{
    __shared__ int bsrc[EPB];
    __shared__ int bloc[EPB];
    __shared__ int cnt, gbase;
    if (threadIdx.x == 0) cnt = 0;
    __syncthreads();

    int ebase = blockIdx.x * EPB;
    #pragma unroll
    for (int i = 0; i < EPB / 256; i++) {
        int e = ebase + i * 256 + threadIdx.x;
        int l = loc[dst[e]];
        if (l >= 0) {
            atomicAdd(&inF1[l], 1);
            int p = atomicAdd(&cnt, 1);
            bsrc[p] = src[e];
            bloc[p] = l;
        }
    }
    __syncthreads();
    if (threadIdx.x == 0) gbase = cnt ? atomicAdd(&counters[2], cnt) : 0;
    __syncthreads();
    for (int p = threadIdx.x; p < cnt; p += 256) {
        int i = gbase + p;
        if (i < E1CAP) { e1src[i] = bsrc[p]; e1loc[i] = bloc[p]; }
    }
}

// K3b: exclusive scan of inF1 -> cursor (single block)
__global__ __launch_bounds__(1024) void k_scan(
    const int* __restrict__ inF1, const int* __restrict__ counters,
    int* __restrict__ cursor)
{
    __shared__ int a[F1CAP], b[F1CAP];   // 32 KB
    int nF1 = min(counters[1], F1CAP);
    int t = threadIdx.x;
    for (int i = t; i < F1CAP; i += 1024) a[i] = (i < nF1) ? inF1[i] : 0;
    __syncthreads();
    int* sp = a; int* dp = b;
    for (int off = 1; off < F1CAP; off <<= 1) {
        for (int i = t; i < F1CAP; i += 1024)
            dp[i] = (i >= off) ? sp[i] + sp[i - off] : sp[i];
        __syncthreads();
        int* tmp = sp; sp = dp; dp = tmp;
    }
    for (int i = t; i < F1CAP; i += 1024)
        cursor[i] = (i == 0) ? 0 : sp[i - 1];
}

// K3c: scatter edges into dst-sorted slots; pack (l<<17)|s in one int
__global__ __launch_bounds__(256) void k_scatter(
    const int* __restrict__ e1src, const int* __restrict__ e1loc,
    const int* __restrict__ counters, int* __restrict__ cursor,
    int* __restrict__ es_pack)
{
    int i = blockIdx.x * 256 + threadIdx.x;
    int nE1 = min(counters[2], E1CAP);
    if (i >= nE1) return;
    int l = e1loc[i];
    int slot = atomicAdd(&cursor[l], 1);
    if (slot < E1CAP) es_pack[slot] = (l << 17) | e1src[i];
}

// K4: MFMA edge-GEMM + fused segmented reduce over sorted dst runs.
// 32 edge rows per block; 4 waves each own 64 output cols.
// agg1[l] += out_norm[s] * relu(x[s] @ wlin + blin) summed over the block's rows.
__global__ __launch_bounds__(256) void k_h0agg(
    const float* __restrict__ x, const unsigned short* __restrict__ wswz,
    const float* __restrict__ blin, const int* __restrict__ es_pack,
    const unsigned int* __restrict__ out_deg, const int* __restrict__ counters,
    float* __restrict__ agg1)
{
    __shared__ unsigned short A[32][136];   // bf16 rows, pad->2-way bank (free)
    __shared__ float T[32][260];            // f32 tile for segmented reduce
    __shared__ float escs[32];
    __shared__ int rdst[32];
    __shared__ int rsrc[32];

    int nE1 = min(counters[2], E1CAP);
    int base = blockIdx.x * 32;
    if (base >= nE1) return;
    int t = threadIdx.x;
    int lane = t & 63, wq = t >> 6;

    if (t < 32) {
        int row = base + t;
        int s = -1, d = -1; float e = 0.f;
        if (row < nE1) {
            int p = es_pack[row];
            s = p & 0x1FFFF; d = p >> 17;
            e = rsqrtf((float)max((int)out_deg[s], 1));
        }
        rsrc[t] = s; rdst[t] = d; escs[t] = e;
    }

    // B fragments for this wave's 4 n-tiles x 4 k-tiles (L2-resident broadcast)
    bf16x8 bfrag[4][4];
    #pragma unroll
    for (int kt = 0; kt < 4; kt++)
        #pragma unroll
        for (int n = 0; n < 4; n++) {
            int ct = wq * 4 + n;
            bfrag[kt][n] = *(const bf16x8*)(wswz + ((kt * 16 + ct) * 64 + lane) * 8);
        }

    __syncthreads();   // rsrc ready

    // gather 32 x-rows -> bf16 LDS
    #pragma unroll
    for (int i = 0; i < 4; i++) {
        int idx = t + i * 256;
        int r = idx >> 5;
        int q = idx & 31;
        int s = rsrc[r];
        float4 v = make_float4(0.f, 0.f, 0.f, 0.f);
        if (s >= 0) v = ((const float4*)(x + (long long)s * IN_DIM_K))[q];
        ushort4 h;
        h.x = f2bf(v.x); h.y = f2bf(v.y); h.z = f2bf(v.z); h.w = f2bf(v.w);
        *(ushort4*)&A[r][q * 4] = h;
    }
    __syncthreads();

    f32x4 acc[2][4];
    #pragma unroll
    for (int m = 0; m < 2; m++)
        #pragma unroll
        for (int n = 0; n < 4; n++) acc[m][n] = (f32x4){0.f, 0.f, 0.f, 0.f};

    const unsigned short* Ab = &A[0][0];
    #pragma unroll
    for (int kt = 0; kt < 4; kt++) {
        bf16x8 a0 = *(const bf16x8*)(Ab + ((lane & 15) * 136 + kt * 32 + (lane >> 4) * 8));
        bf16x8 a1 = *(const bf16x8*)(Ab + (((lane & 15) + 16) * 136 + kt * 32 + (lane >> 4) * 8));
        #pragma unroll
        for (int n = 0; n < 4; n++) {
            acc[0][n] = __builtin_amdgcn_mfma_f32_16x16x32_bf16(a0, bfrag[kt][n], acc[0][n], 0, 0, 0);
            acc[1][n] = __builtin_amdgcn_mfma_f32_16x16x32_bf16(a1, bfrag[kt][n], acc[1][n], 0, 0, 0);
        }
    }

    // epilogue: bias, relu, out_norm scale -> T
    int cbase = lane & 15;
    int rgrp = (lane >> 4) * 4;
    float bj[4];
    #pragma unroll
    for (int n = 0; n < 4; n++) bj[n] = blin[wq * 64 + n * 16 + cbase];
    #pragma unroll
    for (int m = 0; m < 2; m++)
        #pragma unroll
        for (int n = 0; n < 4; n++)
            #pragma unroll
            for (int j = 0; j < 4; j++) {
                int row = m * 16 + rgrp + j;
                int col = wq * 64 + n * 16 + cbase;
                T[row][col] = fmaxf(acc[m][n][j] + bj[n], 0.f) * escs[row];
            }
    __syncthreads();

    // per-column segmented reduce over sorted dst runs; thread t owns col t
    float segs = 0.f; int cur = rdst[0];
    #pragma unroll
    for (int r = 0; r < 32; r++) {
        int d = rdst[r];
        if (d != cur) {
            if (cur >= 0) atomicAdd(&agg1[cur * HID_K + t], segs);
            segs = 0.f; cur = d;
        }
        segs += T[r][t];
    }
    if (cur >= 0) atomicAdd(&agg1[cur * HID_K + t], segs);
}

// K5: h1[l] = relu((agg1[l]*in_norm)@w_c0 + b_c0)
__global__ __launch_bounds__(256) void k_h1(
    const float* __restrict__ agg1, const float* __restrict__ wc0,
    const float* __restrict__ bc0,
    const int* __restrict__ inF1,
    const int* __restrict__ counters, float* __restrict__ h1)
{
    __shared__ float as[16][HID_K];
    __shared__ float ns[16];

    int nF1 = min(counters[1], F1CAP);
    int base = blockIdx.x * 16;
    if (base >= nF1) return;
    int t = threadIdx.x;

    if (t < 16) {
        int l = base + t;
        ns[t] = (l < nF1) ? rsqrtf((float)max(inF1[l], 1)) : 0.f;
    }
    __syncthreads();

    #pragma unroll
    for (int i = 0; i < 4; i++) {
        int idx = t + i * 256;
        int e = idx >> 6;
        int q = idx & 63;
        int l = base + e;
        float4 v = make_float4(0.f, 0.f, 0.f, 0.f);
        if (l < nF1) v = ((const float4*)(agg1 + (long long)l * HID_K))[q];
        float sc = ns[e];
        v.x *= sc; v.y *= sc; v.z *= sc; v.w *= sc;
        ((float4*)as[e])[q] = v;
    }
    __syncthreads();

    float acc[16];
    #pragma unroll
    for (int e = 0; e < 16; e++) acc[e] = 0.f;

    int j = t;
    for (int k = 0; k < HID_K; k += 4) {
        float w0 = wc0[(k + 0) * HID_K + j];
        float w1 = wc0[(k + 1) * HID_K + j];
        float w2 = wc0[(k + 2) * HID_K + j];
        float w3 = wc0[(k + 3) * HID_K + j];
        #pragma unroll
        for (int e = 0; e < 16; e++) {
            float4 av = *(const float4*)&as[e][k];
            acc[e] = fmaf(av.x, w0, acc[e]);
            acc[e] = fmaf(av.y, w1, acc[e]);
            acc[e] = fmaf(av.z, w2, acc[e]);
            acc[e] = fmaf(av.w, w3, acc[e]);
        }
    }

    float bj = bc0[j];
    #pragma unroll
    for (int e = 0; e < 16; e++) {
        int l = base + e;
        if (l < nF1) h1[l * HID_K + j] = fmaxf(acc[e] + bj, 0.f);
    }
}

// K6: agg2[agent] += out_norm[src]*h1[loc[src]]
__global__ __launch_bounds__(256) void k_agg2(
    const int* __restrict__ e0src, const int* __restrict__ e0agent,
    const int* __restrict__ loc, const unsigned int* __restrict__ out_deg,
    const float* __restrict__ h1, const int* __restrict__ counters,
    float* __restrict__ agg2)
{
    int nE0 = min(counters[0], E0CAP);
    int e = blockIdx.x;
    if (e >= nE0) return;
    int s = e0src[e];
    int l = loc[s];
    if (l < 0) return;
    float sc = rsqrtf((float)max((int)out_deg[s], 1));
    int a = e0agent[e];
    int j = threadIdx.x;
    atomicAdd(&agg2[a * HID_K + j], sc * h1[l * HID_K + j]);
}

// K7: per agent: h2 = relu((agg2*in_norm)@w_c1 + b_c1); out = h2@w_emb + b_emb
__global__ __launch_bounds__(256) void k_final(
    const float* __restrict__ agg2, const float* __restrict__ wc1,
    const float* __restrict__ bc1, const float* __restrict__ wemb,
    const float* __restrict__ bemb, const int* __restrict__ inAgent,
    float* __restrict__ out)
{
    __shared__ float a_s[HID_K];
    __shared__ float h2[HID_K];
    int a = blockIdx.x;
    int t = threadIdx.x;

    float n = rsqrtf((float)max(inAgent[a], 1));
    a_s[t] = agg2[a * HID_K + t] * n;
    __syncthreads();

    float acc = 0.f;
    for (int k = 0; k < HID_K; k++)
        acc = fmaf(a_s[k], wc1[k * HID_K + t], acc);
    h2[t] = fmaxf(acc + bc1[t], 0.f);
    __syncthreads();

    if (t < EMB_K) {
        float o = bemb[t];
        for (int k = 0; k < HID_K; k++)
            o = fmaf(h2[k], wemb[k * EMB_K + t], o);
        out[a * EMB_K + t] = o;
    }
}

extern "C" void kernel_launch(void* const* d_in, const int* in_sizes, int n_in,
                              void* d_out, int out_size, void* d_ws, size_t ws_size,
                              hipStream_t stream)
{
    const float* x    = (const float*)d_in[0];
    const int*   src  = (const int*)d_in[1];
    const int*   dst  = (const int*)d_in[2];
    const float* wlin = (const float*)d_in[5];
    const float* blin = (const float*)d_in[6];
    const float* wc0  = (const float*)d_in[7];
    const float* bc0  = (const float*)d_in[8];
    const float* wc1  = (const float*)d_in[9];
    const float* bc1  = (const float*)d_in[10];
    const float* wemb = (const float*)d_in[11];
    const float* bemb = (const float*)d_in[12];
    float* out = (float*)d_out;

    char* ws = (char*)d_ws;
    int*            counters = (int*)(ws + 0);
    int*            inF1     = (int*)(ws + 1024);
    int*            inAgent  = (int*)(ws + 17408);
    int*            flag     = (int*)(ws + 65536);
    int*            es_pack  = (int*)(ws + 65536);      // reuses flag (dead)
    float*          agg2     = (float*)(ws + 589824);
    int*            loc      = (int*)(ws + 655360);
    int*            e0src    = (int*)(ws + 1179648);
    int*            e0agent  = (int*)(ws + 1196032);
    int*            e1src    = (int*)(ws + 1212416);
    int*            e1loc    = (int*)(ws + 1605632);
    unsigned int*   out_deg  = (unsigned int*)(ws + 1998848);
    unsigned short* wswz     = (unsigned short*)(ws + 2523136);
    int*            cursor   = (int*)(ws + 2588672);
    unsigned int*   partial  = (unsigned int*)(ws + 2621440);  // 8 MB, dead after reduce
    float*          agg1     = (float*)(ws + 2621440);         // overlays partial[0:4M]
    float*          h1       = (float*)(ws + 6815744);         // overlays partial[4M:8M]

    hipMemsetAsync(ws, 0, ZERO_SPAN, stream);

    k_wprep<<<16, 256, 0, stream>>>(wlin, wswz);
    k_outdeg_e0<<<G1, 1024, 0, stream>>>(src, dst, partial, flag, counters,
                                         e0src, e0agent, inAgent);
    k_outdeg_reduce<<<HWORDS / 256, 256, 0, stream>>>(partial, out_deg);
    hipMemsetAsync(agg1, 0, (size_t)F1CAP * HID_K * 4, stream);  // partial dead

    k_compact<<<TOTAL_N / 256, 256, 0, stream>>>(flag, loc, counters);
    k_e1_select<<<SCAN_BLOCKS, 256, 0, stream>>>(src, dst, loc, counters,
                                                 e1src, e1loc, inF1);
    k_scan<<<1, 1024, 0, stream>>>(inF1, counters, cursor);
    k_scatter<<<E1CAP / 256, 256, 0, stream>>>(e1src, e1loc, counters, cursor, es_pack);
    k_h0agg<<<E1CAP / 32, 256, 0, stream>>>(x, wswz, blin, es_pack, out_deg,
                                            counters, agg1);
    k_h1<<<F1CAP / 16, 256, 0, stream>>>(agg1, wc0, bc0, inF1, counters, h1);
    k_agg2<<<E0CAP, 256, 0, stream>>>(e0src, e0agent, loc, out_deg, h1,
                                      counters, agg2);
    k_final<<<NAGENT, 256, 0, stream>>>(agg2, wc1, bc1, wemb, bemb, inAgent, out);
}

// Round 5
// 152.447 us; speedup vs baseline: 6.2935x; 1.0734x over previous
//
#include <hip/hip_runtime.h>
#include <hip/hip_bf16.h>

#define TOTAL_N   131072
#define NEDGE     4194304
#define NPG       2048
#define IN_DIM_K  128
#define HID_K     256
#define EMB_K     64
#define NAGENT    64

#define E0CAP     4096
#define F1CAP     4096
#define E1CAP     98304      // 1.5x expected nE1 (~65K)

#define G1        128                 // k_outdeg_e0 blocks
#define EPB1      (NEDGE / G1)        // 32768 edges per block
#define HWORDS    (TOTAL_N / 8)       // 16384 nibble-packed u32 words

#define SCAN_BLOCKS 2048
#define EPB         2048              // NEDGE / SCAN_BLOCKS
#define E1BUF       256               // per-block hit buffer (mean 32 hits)

// ---------------- workspace layout (bytes) ----------------
// zeroed every launch [0, 655360):
//   0        counters  int[256]        ([0]=nE0 [1]=nF1 [2]=nE1)
//   1024     inF1      int[F1CAP]      16K
//   17408    inAgent   int[64]
//   65536    flag      int[TOTAL_N]    512K   (dead after k_compact; reused:)
//     65536    es_pack int[E1CAP]      384K
//   589824   agg2      float[64*HID]   64K
// not zeroed (fully written before read):
//   655360   loc       int[TOTAL_N]    512K
//   1179648  e0src     int[E0CAP]      16K
//   1196032  e0agent   int[E0CAP]      16K
//   1212416  e1src     int[E1CAP]      384K
//   1605632  e1loc     int[E1CAP]      384K
//   1998848  out_deg   u32[TOTAL_N]    512K
//   2523136  wswz      u16[32768]      64K
//   2588672  cursor    int[F1CAP]      16K
//   2605056  bitmap    u64[2048]       16K    (F1 membership, by k_compact)
//   2621440  partial   u32[G1*HWORDS]  8M     (dead after reduce; reused:)
//     2621440  agg1    float[F1CAP*HID] 4M    (memset after reduce)
//     6815744  h1      float[F1CAP*HID] 4M
// total = 11010048 (~10.5 MB)

#define ZERO_SPAN 655360

typedef float f32x4 __attribute__((ext_vector_type(4)));
typedef short bf16x8 __attribute__((ext_vector_type(8)));

__device__ inline unsigned short f2bf(float f) {   // RNE f32->bf16
    unsigned int u = __float_as_uint(f);
    return (unsigned short)((u + 0x7FFFu + ((u >> 16) & 1u)) >> 16);
}

// K0: pre-swizzle wlin into bf16 MFMA B-fragment order
__global__ __launch_bounds__(256) void k_wprep(const float* __restrict__ wlin,
                                               unsigned short* __restrict__ wswz)
{
    int t = blockIdx.x * 256 + threadIdx.x;
    int lane = t & 63;
    int ct = (t >> 6) & 15;
    int kt = t >> 10;
    int colbase = ct * 16 + (lane & 15);
    int kbase = kt * 32 + (lane >> 4) * 8;
    unsigned short o[8];
    #pragma unroll
    for (int i = 0; i < 8; i++) o[i] = f2bf(wlin[(kbase + i) * HID_K + colbase]);
    *(ushort4*)(wswz + t * 8)     = make_ushort4(o[0], o[1], o[2], o[3]);
    *(ushort4*)(wswz + t * 8 + 4) = make_ushort4(o[4], o[5], o[6], o[7]);
}

// K1: out-degree histogram (nibble-packed LDS) + e0 select; int4 edge reads
__global__ __launch_bounds__(1024) void k_outdeg_e0(
    const int* __restrict__ src, const int* __restrict__ dst,
    unsigned int* __restrict__ partial,
    int* __restrict__ flag, int* __restrict__ counters,
    int* __restrict__ e0src, int* __restrict__ e0agent,
    int* __restrict__ inAgent)
{
    __shared__ unsigned int hist[HWORDS];   // 64 KB
    __shared__ int bs[1024], ba[1024];
    __shared__ int cnt, gbase;
    int t = threadIdx.x;
    for (int i = t; i < HWORDS; i += 1024) hist[i] = 0u;
    if (t == 0) cnt = 0;
    __syncthreads();

    int ebase = blockIdx.x * EPB1;
    const int4* s4 = (const int4*)(src + ebase);
    const int4* d4 = (const int4*)(dst + ebase);
    #pragma unroll 2
    for (int i = 0; i < EPB1 / 4096; i++) {     // 8 iterations
        int4 sv = s4[i * 1024 + t];
        int4 dv = d4[i * 1024 + t];
        int ss[4] = {sv.x, sv.y, sv.z, sv.w};
        int dd[4] = {dv.x, dv.y, dv.z, dv.w};
        #pragma unroll
        for (int j = 0; j < 4; j++) {
            int s = ss[j], d = dd[j];
            atomicAdd(&hist[s >> 3], 1u << ((s & 7) * 4));
            if ((d & (NPG - 1)) == 0) {
                flag[s] = 1;
                int p = atomicAdd(&cnt, 1);
                if (p < 1024) { bs[p] = s; ba[p] = d >> 11; }
                else {
                    int gi = atomicAdd(&counters[0], 1);
                    if (gi < E0CAP) { e0src[gi] = s; e0agent[gi] = d >> 11; }
                    atomicAdd(&inAgent[d >> 11], 1);
                }
            }
        }
    }
    __syncthreads();
    int c = min(cnt, 1024);
    if (t == 0) gbase = c ? atomicAdd(&counters[0], c) : 0;
    __syncthreads();
    if (t < c) {
        int i = gbase + t;
        if (i < E0CAP) { e0src[i] = bs[t]; e0agent[i] = ba[t]; }
        atomicAdd(&inAgent[ba[t]], 1);
    }
    unsigned int* pout = partial + blockIdx.x * HWORDS;
    for (int i = t; i < HWORDS; i += 1024) pout[i] = hist[i];
}

// K1b: reduce nibble partials -> u32 out_deg (SWAR u8 lanes)
__global__ __launch_bounds__(256) void k_outdeg_reduce(
    const unsigned int* __restrict__ partial, unsigned int* __restrict__ out_deg)
{
    int w = blockIdx.x * 256 + threadIdx.x;
    unsigned int accE = 0, accO = 0;
    #pragma unroll 8
    for (int g = 0; g < G1; g++) {
        unsigned int v = partial[g * HWORDS + w];
        accE += v & 0x0F0F0F0Fu;
        accO += (v >> 4) & 0x0F0F0F0Fu;
    }
    uint4 lo = make_uint4(accE & 255u, accO & 255u, (accE >> 8) & 255u, (accO >> 8) & 255u);
    uint4 hi = make_uint4((accE >> 16) & 255u, (accO >> 16) & 255u, (accE >> 24) & 255u, (accO >> 24) & 255u);
    ((uint4*)(out_deg + 8 * w))[0] = lo;
    ((uint4*)(out_deg + 8 * w))[1] = hi;
}

// K2: compact frontier F1 + emit membership bitmap (1 ballot word per wave)
__global__ __launch_bounds__(256) void k_compact(
    const int* __restrict__ flag, int* __restrict__ loc,
    int* __restrict__ counters, unsigned long long* __restrict__ bitmap)
{
    __shared__ int cnt, gbase;
    if (threadIdx.x == 0) cnt = 0;
    __syncthreads();
    int v = blockIdx.x * 256 + threadIdx.x;
    int f = flag[v];
    unsigned long long m = __ballot(f != 0);
    if ((threadIdx.x & 63) == 0) bitmap[v >> 6] = m;
    int p = -1;
    if (f) p = atomicAdd(&cnt, 1);
    __syncthreads();
    if (threadIdx.x == 0) gbase = cnt ? atomicAdd(&counters[1], cnt) : 0;
    __syncthreads();
    int l = -1;
    if (p >= 0) {
        int id = gbase + p;
        if (id < F1CAP) l = id;
    }
    loc[v] = l;
}

// K3: select edges with dst in F1 — LDS bitmap test, loc gather only on hit
__global__ __launch_bounds__(256) void k_e1_select(
    const int* __restrict__ src, const int* __restrict__ dst,
    const int* __restrict__ loc, const unsigned int* __restrict__ bitmap,
    int* __restrict__ counters,
    int* __restrict__ e1src, int* __restrict__ e1loc,
    int* __restrict__ inF1)
{
    __shared__ unsigned int bm[TOTAL_N / 32];   // 16 KB
    __shared__ int bsrc[E1BUF], bloc[E1BUF];
    __shared__ int cnt, gbase;
    int t = threadIdx.x;
    #pragma unroll
    for (int i = 0; i < 4; i++)
        ((uint4*)bm)[t + i * 256] = ((const uint4*)bitmap)[t + i * 256];
    if (t == 0) cnt = 0;
    __syncthreads();

    int ebase = blockIdx.x * EPB;
    const int4* d4p = (const int4*)(dst + ebase);
    #pragma unroll
    for (int i = 0; i < EPB / 1024; i++) {      // 2 iterations
        int4 d4 = d4p[i * 256 + t];
        int eidx = ebase + (i * 256 + t) * 4;
        int dd[4] = {d4.x, d4.y, d4.z, d4.w};
        #pragma unroll
        for (int j = 0; j < 4; j++) {
            int d = dd[j];
            if ((bm[d >> 5] >> (d & 31)) & 1u) {
                int l = loc[d];
                if (l >= 0) {
                    atomicAdd(&inF1[l], 1);
                    int s = src[eidx + j];
                    int p = atomicAdd(&cnt, 1);
                    if (p < E1BUF) { bsrc[p] = s; bloc[p] = l; }
                    else {          // rare overflow: direct global slot
                        int gi = atomicAdd(&counters[2], 1);
                        if (gi < E1CAP) { e1src[gi] = s; e1loc[gi] = l; }
                    }
                }
            }
        }
    }
    __syncthreads();
    int c = min(cnt, E1BUF);
    if (t == 0) gbase = c ? atomicAdd(&counters[2], c) : 0;
    __syncthreads();
    if (t < c) {
        int i = gbase + t;
        if (i < E1CAP) { e1src[i] = bsrc[t]; e1loc[i] = bloc[t]; }
    }
}

// K3b: exclusive scan of inF1 -> cursor (single block)
__global__ __launch_bounds__(1024) void k_scan(
    const int* __restrict__ inF1, const int* __restrict__ counters,
    int* __restrict__ cursor)
{
    __shared__ int a[F1CAP], b[F1CAP];
    int nF1 = min(counters[1], F1CAP);
    int t = threadIdx.x;
    for (int i = t; i < F1CAP; i += 1024) a[i] = (i < nF1) ? inF1[i] : 0;
    __syncthreads();
    int* sp = a; int* dp = b;
    for (int off = 1; off < F1CAP; off <<= 1) {
        for (int i = t; i < F1CAP; i += 1024)
            dp[i] = (i >= off) ? sp[i] + sp[i - off] : sp[i];
        __syncthreads();
        int* tmp = sp; sp = dp; dp = tmp;
    }
    for (int i = t; i < F1CAP; i += 1024)
        cursor[i] = (i == 0) ? 0 : sp[i - 1];
}

// K3c: scatter edges into dst-sorted slots; pack (l<<17)|s
__global__ __launch_bounds__(256) void k_scatter(
    const int* __restrict__ e1src, const int* __restrict__ e1loc,
    const int* __restrict__ counters, int* __restrict__ cursor,
    int* __restrict__ es_pack)
{
    int i = blockIdx.x * 256 + threadIdx.x;
    int nE1 = min(counters[2], E1CAP);
    if (i >= nE1) return;
    int l = e1loc[i];
    int slot = atomicAdd(&cursor[l], 1);
    if (slot < E1CAP) es_pack[slot] = (l << 17) | e1src[i];
}

// K4: MFMA edge-GEMM + fused segmented reduce over sorted dst runs
__global__ __launch_bounds__(256) void k_h0agg(
    const float* __restrict__ x, const unsigned short* __restrict__ wswz,
    const float* __restrict__ blin, const int* __restrict__ es_pack,
    const unsigned int* __restrict__ out_deg, const int* __restrict__ counters,
    float* __restrict__ agg1)
{
    __shared__ unsigned short A[32][136];
    __shared__ float T[32][260];
    __shared__ float escs[32];
    __shared__ int rdst[32];
    __shared__ int rsrc[32];

    int nE1 = min(counters[2], E1CAP);
    int base = blockIdx.x * 32;
    if (base >= nE1) return;
    int t = threadIdx.x;
    int lane = t & 63, wq = t >> 6;

    if (t < 32) {
        int row = base + t;
        int s = -1, d = -1; float e = 0.f;
        if (row < nE1) {
            int p = es_pack[row];
            s = p & 0x1FFFF; d = p >> 17;
            e = rsqrtf((float)max((int)out_deg[s], 1));
        }
        rsrc[t] = s; rdst[t] = d; escs[t] = e;
    }

    bf16x8 bfrag[4][4];
    #pragma unroll
    for (int kt = 0; kt < 4; kt++)
        #pragma unroll
        for (int n = 0; n < 4; n++) {
            int ct = wq * 4 + n;
            bfrag[kt][n] = *(const bf16x8*)(wswz + ((kt * 16 + ct) * 64 + lane) * 8);
        }

    __syncthreads();

    #pragma unroll
    for (int i = 0; i < 4; i++) {
        int idx = t + i * 256;
        int r = idx >> 5;
        int q = idx & 31;
        int s = rsrc[r];
        float4 v = make_float4(0.f, 0.f, 0.f, 0.f);
        if (s >= 0) v = ((const float4*)(x + (long long)s * IN_DIM_K))[q];
        ushort4 h;
        h.x = f2bf(v.x); h.y = f2bf(v.y); h.z = f2bf(v.z); h.w = f2bf(v.w);
        *(ushort4*)&A[r][q * 4] = h;
    }
    __syncthreads();

    f32x4 acc[2][4];
    #pragma unroll
    for (int m = 0; m < 2; m++)
        #pragma unroll
        for (int n = 0; n < 4; n++) acc[m][n] = (f32x4){0.f, 0.f, 0.f, 0.f};

    const unsigned short* Ab = &A[0][0];
    #pragma unroll
    for (int kt = 0; kt < 4; kt++) {
        bf16x8 a0 = *(const bf16x8*)(Ab + ((lane & 15) * 136 + kt * 32 + (lane >> 4) * 8));
        bf16x8 a1 = *(const bf16x8*)(Ab + (((lane & 15) + 16) * 136 + kt * 32 + (lane >> 4) * 8));
        #pragma unroll
        for (int n = 0; n < 4; n++) {
            acc[0][n] = __builtin_amdgcn_mfma_f32_16x16x32_bf16(a0, bfrag[kt][n], acc[0][n], 0, 0, 0);
            acc[1][n] = __builtin_amdgcn_mfma_f32_16x16x32_bf16(a1, bfrag[kt][n], acc[1][n], 0, 0, 0);
        }
    }

    int cbase = lane & 15;
    int rgrp = (lane >> 4) * 4;
    float bj[4];
    #pragma unroll
    for (int n = 0; n < 4; n++) bj[n] = blin[wq * 64 + n * 16 + cbase];
    #pragma unroll
    for (int m = 0; m < 2; m++)
        #pragma unroll
        for (int n = 0; n < 4; n++)
            #pragma unroll
            for (int j = 0; j < 4; j++) {
                int row = m * 16 + rgrp + j;
                int col = wq * 64 + n * 16 + cbase;
                T[row][col] = fmaxf(acc[m][n][j] + bj[n], 0.f) * escs[row];
            }
    __syncthreads();

    float segs = 0.f; int cur = rdst[0];
    #pragma unroll
    for (int r = 0; r < 32; r++) {
        int d = rdst[r];
        if (d != cur) {
            if (cur >= 0) atomicAdd(&agg1[cur * HID_K + t], segs);
            segs = 0.f; cur = d;
        }
        segs += T[r][t];
    }
    if (cur >= 0) atomicAdd(&agg1[cur * HID_K + t], segs);
}

// K5: h1[l] = relu((agg1[l]*in_norm)@w_c0 + b_c0)
__global__ __launch_bounds__(256) void k_h1(
    const float* __restrict__ agg1, const float* __restrict__ wc0,
    const float* __restrict__ bc0,
    const int* __restrict__ inF1,
    const int* __restrict__ counters, float* __restrict__ h1)
{
    __shared__ float as[16][HID_K];
    __shared__ float ns[16];

    int nF1 = min(counters[1], F1CAP);
    int base = blockIdx.x * 16;
    if (base >= nF1) return;
    int t = threadIdx.x;

    if (t < 16) {
        int l = base + t;
        ns[t] = (l < nF1) ? rsqrtf((float)max(inF1[l], 1)) : 0.f;
    }
    __syncthreads();

    #pragma unroll
    for (int i = 0; i < 4; i++) {
        int idx = t + i * 256;
        int e = idx >> 6;
        int q = idx & 63;
        int l = base + e;
        float4 v = make_float4(0.f, 0.f, 0.f, 0.f);
        if (l < nF1) v = ((const float4*)(agg1 + (long long)l * HID_K))[q];
        float sc = ns[e];
        v.x *= sc; v.y *= sc; v.z *= sc; v.w *= sc;
        ((float4*)as[e])[q] = v;
    }
    __syncthreads();

    float acc[16];
    #pragma unroll
    for (int e = 0; e < 16; e++) acc[e] = 0.f;

    int j = t;
    for (int k = 0; k < HID_K; k += 4) {
        float w0 = wc0[(k + 0) * HID_K + j];
        float w1 = wc0[(k + 1) * HID_K + j];
        float w2 = wc0[(k + 2) * HID_K + j];
        float w3 = wc0[(k + 3) * HID_K + j];
        #pragma unroll
        for (int e = 0; e < 16; e++) {
            float4 av = *(const float4*)&as[e][k];
            acc[e] = fmaf(av.x, w0, acc[e]);
            acc[e] = fmaf(av.y, w1, acc[e]);
            acc[e] = fmaf(av.z, w2, acc[e]);
            acc[e] = fmaf(av.w, w3, acc[e]);
        }
    }

    float bj = bc0[j];
    #pragma unroll
    for (int e = 0; e < 16; e++) {
        int l = base + e;
        if (l < nF1) h1[l * HID_K + j] = fmaxf(acc[e] + bj, 0.f);
    }
}

// K6: agg2[agent] += out_norm[src]*h1[loc[src]]
__global__ __launch_bounds__(256) void k_agg2(
    const int* __restrict__ e0src, const int* __restrict__ e0agent,
    const int* __restrict__ loc, const unsigned int* __restrict__ out_deg,
    const float* __restrict__ h1, const int* __restrict__ counters,
    float* __restrict__ agg2)
{
    int nE0 = min(counters[0], E0CAP);
    int e = blockIdx.x;
    if (e >= nE0) return;
    int s = e0src[e];
    int l = loc[s];
    if (l < 0) return;
    float sc = rsqrtf((float)max((int)out_deg[s], 1));
    int a = e0agent[e];
    int j = threadIdx.x;
    atomicAdd(&agg2[a * HID_K + j], sc * h1[l * HID_K + j]);
}

// K7: per agent: h2 = relu((agg2*in_norm)@w_c1 + b_c1); out = h2@w_emb + b_emb
__global__ __launch_bounds__(256) void k_final(
    const float* __restrict__ agg2, const float* __restrict__ wc1,
    const float* __restrict__ bc1, const float* __restrict__ wemb,
    const float* __restrict__ bemb, const int* __restrict__ inAgent,
    float* __restrict__ out)
{
    __shared__ float a_s[HID_K];
    __shared__ float h2[HID_K];
    int a = blockIdx.x;
    int t = threadIdx.x;

    float n = rsqrtf((float)max(inAgent[a], 1));
    a_s[t] = agg2[a * HID_K + t] * n;
    __syncthreads();

    float acc = 0.f;
    for (int k = 0; k < HID_K; k++)
        acc = fmaf(a_s[k], wc1[k * HID_K + t], acc);
    h2[t] = fmaxf(acc + bc1[t], 0.f);
    __syncthreads();

    if (t < EMB_K) {
        float o = bemb[t];
        for (int k = 0; k < HID_K; k++)
            o = fmaf(h2[k], wemb[k * EMB_K + t], o);
        out[a * EMB_K + t] = o;
    }
}

extern "C" void kernel_launch(void* const* d_in, const int* in_sizes, int n_in,
                              void* d_out, int out_size, void* d_ws, size_t ws_size,
                              hipStream_t stream)
{
    const float* x    = (const float*)d_in[0];
    const int*   src  = (const int*)d_in[1];
    const int*   dst  = (const int*)d_in[2];
    const float* wlin = (const float*)d_in[5];
    const float* blin = (const float*)d_in[6];
    const float* wc0  = (const float*)d_in[7];
    const float* bc0  = (const float*)d_in[8];
    const float* wc1  = (const float*)d_in[9];
    const float* bc1  = (const float*)d_in[10];
    const float* wemb = (const float*)d_in[11];
    const float* bemb = (const float*)d_in[12];
    float* out = (float*)d_out;

    char* ws = (char*)d_ws;
    int*                counters = (int*)(ws + 0);
    int*                inF1     = (int*)(ws + 1024);
    int*                inAgent  = (int*)(ws + 17408);
    int*                flag     = (int*)(ws + 65536);
    int*                es_pack  = (int*)(ws + 65536);      // reuses flag (dead)
    float*              agg2     = (float*)(ws + 589824);
    int*                loc      = (int*)(ws + 655360);
    int*                e0src    = (int*)(ws + 1179648);
    int*                e0agent  = (int*)(ws + 1196032);
    int*                e1src    = (int*)(ws + 1212416);
    int*                e1loc    = (int*)(ws + 1605632);
    unsigned int*       out_deg  = (unsigned int*)(ws + 1998848);
    unsigned short*     wswz     = (unsigned short*)(ws + 2523136);
    int*                cursor   = (int*)(ws + 2588672);
    unsigned long long* bitmap   = (unsigned long long*)(ws + 2605056);
    unsigned int*       partial  = (unsigned int*)(ws + 2621440);  // dead after reduce
    float*              agg1     = (float*)(ws + 2621440);
    float*              h1       = (float*)(ws + 6815744);

    hipMemsetAsync(ws, 0, ZERO_SPAN, stream);

    k_wprep<<<16, 256, 0, stream>>>(wlin, wswz);
    k_outdeg_e0<<<G1, 1024, 0, stream>>>(src, dst, partial, flag, counters,
                                         e0src, e0agent, inAgent);
    k_outdeg_reduce<<<HWORDS / 256, 256, 0, stream>>>(partial, out_deg);
    hipMemsetAsync(agg1, 0, (size_t)F1CAP * HID_K * 4, stream);  // partial dead

    k_compact<<<TOTAL_N / 256, 256, 0, stream>>>(flag, loc, counters, bitmap);
    k_e1_select<<<SCAN_BLOCKS, 256, 0, stream>>>(src, dst, loc,
                                                 (const unsigned int*)bitmap,
                                                 counters, e1src, e1loc, inF1);
    k_scan<<<1, 1024, 0, stream>>>(inF1, counters, cursor);
    k_scatter<<<E1CAP / 256, 256, 0, stream>>>(e1src, e1loc, counters, cursor, es_pack);
    k_h0agg<<<E1CAP / 32, 256, 0, stream>>>(x, wswz, blin, es_pack, out_deg,
                                            counters, agg1);
    k_h1<<<F1CAP / 16, 256, 0, stream>>>(agg1, wc0, bc0, inF1, counters, h1);
    k_agg2<<<E0CAP, 256, 0, stream>>>(e0src, e0agent, loc, out_deg, h1,
                                      counters, agg2);
    k_final<<<NAGENT, 256, 0, stream>>>(agg2, wc1, bc1, wemb, bemb, inAgent, out);
}